// Round 3
// baseline (3336.097 us; speedup 1.0000x reference)
//
#include <hip/hip_runtime.h>

#define TT    1024   // timesteps
#define BATCH 2048
#define NI    6      // input dim
#define NH    38     // hidden
#define NCLS  8      // classes
#define NB    4      // batches per block  -> grid 512 = 2 blocks/CU
#define HP1   48     // h1 row: h(38) pad(2) x(6) pad(2)  (16B-aligned)
#define HP2   40     // h2 row: h(38) pad(2)
#define XOFF  40     // x offset inside h1 row
#define BLK   512

typedef float4 F4;
typedef float2 F2;

__device__ __forceinline__ float fsig(float v)  { return __fdividef(1.0f, 1.0f + __expf(-v)); }
__device__ __forceinline__ float ftanh(float v) { return 1.0f - __fdividef(2.0f, 1.0f + __expf(2.0f * v)); }

// augmented L1 weight element: cols 0..37 = Whh0, cols 40..45 = Wih0, else 0
__device__ __forceinline__ float augw(const float* Whh, const float* Wih, int row, int c) {
    if (c < NH) return Whh[row * NH + c];
    if (c >= XOFF && c < XOFF + NI) return Wih[row * NI + (c - XOFF)];
    return 0.0f;
}
__device__ __forceinline__ F4 aug4(const float* Whh, const float* Wih, int row, int c) {
    F4 v; v.x = augw(Whh, Wih, row, c + 0); v.y = augw(Whh, Wih, row, c + 1);
    v.z = augw(Whh, Wih, row, c + 2); v.w = augw(Whh, Wih, row, c + 3); return v;
}
__device__ __forceinline__ F2 ldw2(const float* W, int row, int c) {
    F2 v; v.x = (c     < NH) ? W[row * NH + c    ] : 0.0f;
          v.y = (c + 1 < NH) ? W[row * NH + c + 1] : 0.0f; return v;
}

// ---------- macro-unrolled bodies: no per-thread arrays anywhere ----------

#define DOT12(ACC, WA, WB, WC) \
    ACC += WA.x*hA.x; ACC += WA.y*hA.y; ACC += WA.z*hA.z; ACC += WA.w*hA.w; \
    ACC += WB.x*hB.x; ACC += WB.y*hB.y; ACC += WB.z*hB.z; ACC += WB.w*hB.w; \
    ACC += WC.x*hC.x; ACC += WC.y*hC.y; ACC += WC.z*hC.z; ACC += WC.w*hC.w;

#define L1BATCH(bb, PRV) { \
    const float* hr = &h1buf[PRV][bb][l1o]; \
    const F4 hA = *(const F4*)(hr + 0), hB = *(const F4*)(hr + 4), hC = *(const F4*)(hr + 8); \
    DOT12(a##bb##0, w0a, w0b, w0c) DOT12(a##bb##1, w1a, w1b, w1c) \
    DOT12(a##bb##2, w2a, w2b, w2c) DOT12(a##bb##3, w3a, w3b, w3c) }

#define DOT10(ACC, U0, U1, U2, U3, U4) \
    ACC += U0.x*e0.x; ACC += U0.y*e0.y; ACC += U1.x*e1.x; ACC += U1.y*e1.y; \
    ACC += U2.x*e2.x; ACC += U2.y*e2.y; ACC += U3.x*e3.x; ACC += U3.y*e3.y; \
    ACC += U4.x*e4.x; ACC += U4.y*e4.y;

#define L2BATCH(bb, BASE) { \
    const float* hr = (BASE) + (bb) * l2str; \
    const F2 e0 = *(const F2*)(hr + 0), e1 = *(const F2*)(hr + 2), e2 = *(const F2*)(hr + 4), \
             e3 = *(const F2*)(hr + 6), e4 = *(const F2*)(hr + 8); \
    DOT10(a##bb##0, u00, u01, u02, u03, u04) DOT10(a##bb##1, u10, u11, u12, u13, u14) \
    DOT10(a##bb##2, u20, u21, u22, u23, u24) DOT10(a##bb##3, u30, u31, u32, u33, u34) }

#define BF(mask) \
    a00 += __shfl_xor(a00, mask); a01 += __shfl_xor(a01, mask); \
    a02 += __shfl_xor(a02, mask); a03 += __shfl_xor(a03, mask); \
    a10 += __shfl_xor(a10, mask); a11 += __shfl_xor(a11, mask); \
    a12 += __shfl_xor(a12, mask); a13 += __shfl_xor(a13, mask); \
    a20 += __shfl_xor(a20, mask); a21 += __shfl_xor(a21, mask); \
    a22 += __shfl_xor(a22, mask); a23 += __shfl_xor(a23, mask); \
    a30 += __shfl_xor(a30, mask); a31 += __shfl_xor(a31, mask); \
    a32 += __shfl_xor(a32, mask); a33 += __shfl_xor(a33, mask);

// 4-way select by (sub&1, sub&2): batch index = sub&3 (valid for L1 sub 0..3 and L2 sub 0..7)
#define SEL4(g) ({ const float v01_ = (sub & 1) ? a1##g : a0##g; \
                   const float v23_ = (sub & 1) ? a3##g : a2##g; \
                   (sub & 2) ? v23_ : v01_; })

#define ACCDECL \
    float a00=0.f,a01=0.f,a02=0.f,a03=0.f, a10=0.f,a11=0.f,a12=0.f,a13=0.f; \
    float a20=0.f,a21=0.f,a22=0.f,a23=0.f, a30=0.f,a31=0.f,a32=0.f,a33=0.f;

#define L1BODY(WL, PRV) { \
    ACCDECL \
    L1BATCH(0, PRV) L1BATCH(1, PRV) L1BATCH(2, PRV) L1BATCH(3, PRV) \
    BF(1) BF(2) \
    const float pv0 = bs0 + SEL4(0), pv1 = bs1 + SEL4(1); \
    const float pv2 = bs2 + SEL4(2), pv3 = bs3 + SEL4(3); \
    const float ig = fsig(pv0), fg = fsig(pv1), gg = ftanh(pv2), og = fsig(pv3); \
    const float cc = fg * cl0 + ig * gg; cl0 = cc; \
    *(WL) = og * ftanh(cc); }

#define L2BODY(BASE, WH2) { \
    ACCDECL \
    L2BATCH(0, BASE) L2BATCH(1, BASE) L2BATCH(2, BASE) L2BATCH(3, BASE) \
    BF(1) BF(2) \
    float t0 = SEL4(0), t1 = SEL4(1), t2 = SEL4(2), t3 = SEL4(3); \
    t0 += __shfl_xor(t0, 4); t1 += __shfl_xor(t1, 4); \
    t2 += __shfl_xor(t2, 4); t3 += __shfl_xor(t3, 4); \
    const float ig = fsig(bs0 + t0), fg = fsig(bs1 + t1); \
    const float gg = ftanh(bs2 + t2), og = fsig(bs3 + t3); \
    const float cc = fg * cl0 + ig * gg; cl0 = cc; \
    if (sub < 4) *(WH2) = og * ftanh(cc); }

// One pipeline iteration. PF load issued FIRST (T14: issue-early / write-late).
#define ITER(L1GO, L2GO, TNX, WL, PRV, BASE, WH2, PW) { \
    const int tnx_ = (TNX); \
    const bool pfgo_ = isPF && (tnx_ < TT); \
    float pfv_ = 0.0f; \
    if (pfgo_) pfv_ = xg[(size_t)tnx_ * NI]; \
    if (isL1) { if (L1GO) { L1BODY(WL, PRV) } } \
    else if (isL2) { if (L2GO) { L2BODY(BASE, WH2) } } \
    if (pfgo_) *(PW) = pfv_; \
    __syncthreads(); }

// Role layout (8 waves / 512 threads), skewed pipeline, one barrier/iter:
//   tid   0..151 : L1. sub=tid&3 (12-col slice of augmented 48-col row), u=tid>>2.
//                  48 weight floats; 4 batches x 4 gates x 12 FMA; BF(1,2); batch=sub.
//   tid 152..175 : x prefetch, 1 element each (writes into h1buf x-columns).
//   tid 192..495 : L2. m=tid-192, sub=m&7, u=m>>3. subs 0-3: Wih1 cols 10s..;
//                  subs 4-7: Whh1. 40 weight floats; BF(1,2) + trimmed xor-4; batch=sub&3.
//   others       : idle.
// Iter i: L1 -> h1(i) (reads h1buf[prv]: h(i-1) + x(i)); L2 -> h2(i-1)
// (reads h1buf[prv], h2buf[cur]=h2(i-2), writes h2buf[prv]). Final h2(TT-1) in h2buf[1].

__global__ __launch_bounds__(BLK, 4) void lstm2_kernel(
    const float* __restrict__ x,
    const float* __restrict__ Wih0, const float* __restrict__ Whh0, const float* __restrict__ b0,
    const float* __restrict__ Wih1, const float* __restrict__ Whh1, const float* __restrict__ b1,
    const float* __restrict__ Wc,   const float* __restrict__ bc,
    float* __restrict__ out)
{
    __shared__ __align__(16) float h1buf[2][NB][HP1];
    __shared__ __align__(16) float h2buf[2][NB][HP2];

    const int tid   = threadIdx.x;
    const int bbase = blockIdx.x * NB;

    // zero both state buffers (pads + x slots start at 0)
    for (int idx = tid; idx < 2 * NB * HP1; idx += BLK) (&h1buf[0][0][0])[idx] = 0.0f;
    for (int idx = tid; idx < 2 * NB * HP2; idx += BLK) (&h2buf[0][0][0])[idx] = 0.0f;
    __syncthreads();
    // x(0) into slot 1 (iter 0 reads prv=1)
    if (tid < NB * NI) {
        const int b = tid / NI, j = tid % NI;
        h1buf[1][b][XOFF + j] = x[(size_t)(bbase + b) * TT * NI + j];
    }

    const bool isL1 = (tid < 152);
    const bool isPF = (tid >= 152) && (tid < 152 + NB * NI);
    const bool isL2 = (tid >= 192) && (tid < 192 + 304);

    int sub = 0, u = 0;
    if (isL1)      { sub = tid & 3; u = tid >> 2; }
    else if (isL2) { const int m = tid - 192; sub = m & 7; u = m >> 3; }

    // ---- named weight registers ----
    F4 w0a, w0b, w0c, w1a, w1b, w1c, w2a, w2b, w2c, w3a, w3b, w3c;   // L1: 4 gates x 3 F4
    F2 u00,u01,u02,u03,u04, u10,u11,u12,u13,u14;                      // L2: 4 gates x 5 F2
    F2 u20,u21,u22,u23,u24, u30,u31,u32,u33,u34;
    {
        const F4 z4 = {0.f,0.f,0.f,0.f}; const F2 z2 = {0.f,0.f};
        w0a=z4;w0b=z4;w0c=z4; w1a=z4;w1b=z4;w1c=z4; w2a=z4;w2b=z4;w2c=z4; w3a=z4;w3b=z4;w3c=z4;
        u00=z2;u01=z2;u02=z2;u03=z2;u04=z2; u10=z2;u11=z2;u12=z2;u13=z2;u14=z2;
        u20=z2;u21=z2;u22=z2;u23=z2;u24=z2; u30=z2;u31=z2;u32=z2;u33=z2;u34=z2;
    }
    float bs0 = 0.f, bs1 = 0.f, bs2 = 0.f, bs3 = 0.f;

    int l1o = 0, l2str = 0;
    float *wl0 = nullptr, *wl1 = nullptr, *wp0 = nullptr, *wp1 = nullptr, *pw0 = nullptr, *pw1 = nullptr;
    const float *l2b0 = nullptr, *l2b1 = nullptr, *xg = nullptr;

    if (isL1) {
        l1o = 12 * sub;
        const int c = l1o;
        w0a = aug4(Whh0, Wih0, u + 0*NH, c);   w0b = aug4(Whh0, Wih0, u + 0*NH, c + 4);
        w0c = aug4(Whh0, Wih0, u + 0*NH, c+8);
        w1a = aug4(Whh0, Wih0, u + 1*NH, c);   w1b = aug4(Whh0, Wih0, u + 1*NH, c + 4);
        w1c = aug4(Whh0, Wih0, u + 1*NH, c+8);
        w2a = aug4(Whh0, Wih0, u + 2*NH, c);   w2b = aug4(Whh0, Wih0, u + 2*NH, c + 4);
        w2c = aug4(Whh0, Wih0, u + 2*NH, c+8);
        w3a = aug4(Whh0, Wih0, u + 3*NH, c);   w3b = aug4(Whh0, Wih0, u + 3*NH, c + 4);
        w3c = aug4(Whh0, Wih0, u + 3*NH, c+8);
        bs0 = b0[u]; bs1 = b0[u + NH]; bs2 = b0[u + 2*NH]; bs3 = b0[u + 3*NH];
        wl0 = &h1buf[0][sub][u]; wl1 = &h1buf[1][sub][u];
    } else if (isL2) {
        const float* Wm = (sub < 4) ? Wih1 : Whh1;
        const int c = 10 * (sub & 3);
        u00 = ldw2(Wm, u + 0*NH, c); u01 = ldw2(Wm, u + 0*NH, c+2); u02 = ldw2(Wm, u + 0*NH, c+4);
        u03 = ldw2(Wm, u + 0*NH, c+6); u04 = ldw2(Wm, u + 0*NH, c+8);
        u10 = ldw2(Wm, u + 1*NH, c); u11 = ldw2(Wm, u + 1*NH, c+2); u12 = ldw2(Wm, u + 1*NH, c+4);
        u13 = ldw2(Wm, u + 1*NH, c+6); u14 = ldw2(Wm, u + 1*NH, c+8);
        u20 = ldw2(Wm, u + 2*NH, c); u21 = ldw2(Wm, u + 2*NH, c+2); u22 = ldw2(Wm, u + 2*NH, c+4);
        u23 = ldw2(Wm, u + 2*NH, c+6); u24 = ldw2(Wm, u + 2*NH, c+8);
        u30 = ldw2(Wm, u + 3*NH, c); u31 = ldw2(Wm, u + 3*NH, c+2); u32 = ldw2(Wm, u + 3*NH, c+4);
        u33 = ldw2(Wm, u + 3*NH, c+6); u34 = ldw2(Wm, u + 3*NH, c+8);
        bs0 = b1[u]; bs1 = b1[u + NH]; bs2 = b1[u + 2*NH]; bs3 = b1[u + 3*NH];
        l2str = (sub < 4) ? HP1 : HP2;
        l2b0 = (sub < 4) ? &h1buf[1][0][10 * sub] : &h2buf[0][0][10 * (sub - 4)];  // CUR=0
        l2b1 = (sub < 4) ? &h1buf[0][0][10 * sub] : &h2buf[1][0][10 * (sub - 4)];  // CUR=1
        wp0 = &h2buf[1][sub & 3][u];   // CUR=0 -> write PRV=1
        wp1 = &h2buf[0][sub & 3][u];   // CUR=1 -> write PRV=0
    } else if (isPF) {
        const int e = tid - 152, b = e / NI, j = e % NI;
        xg  = x + (size_t)(bbase + b) * TT * NI + j;
        pw0 = &h1buf[0][b][XOFF + j];  // consumed next iter (CUR=0 now)
        pw1 = &h1buf[1][b][XOFF + j];
    }

    float cl0 = 0.0f;   // cell state: L1 batch `sub`, L2 batch `sub&3`

    __syncthreads();

    // iter 0: CUR=0, PRV=1 (L1 only; PF x(1) -> h1buf[0])
    ITER(true, false, 1, wl0, 1, l2b0, wp0, pw0)

    // pairs (i, i+1) for i = 1,3,...,1023  -> iterations 1..1024
    #pragma unroll 1
    for (int i = 1; i < TT; i += 2) {
        // iter i   : CUR=1, PRV=0
        ITER(true, true, i + 1, wl1, 0, l2b1, wp1, pw1)
        // iter i+1 : CUR=0, PRV=1
        ITER(i + 1 < TT, true, i + 2, wl0, 1, l2b0, wp0, pw0)
    }

    // epilogue: out = h2(TT-1) @ Wc.T + bc ; final h2 in h2buf[1]
    if (tid < NB * NCLS) {
        const int b = tid >> 3, c = tid & 7;
        float acc = bc[c];
        #pragma unroll
        for (int k = 0; k < NH; ++k) acc += Wc[c * NH + k] * h2buf[1][b][k];
        out[(size_t)(bbase + b) * NCLS + c] = acc;
    }
}

extern "C" void kernel_launch(void* const* d_in, const int* in_sizes, int n_in,
                              void* d_out, int out_size, void* d_ws, size_t ws_size,
                              hipStream_t stream) {
    const float* x    = (const float*)d_in[0];
    const float* Wih0 = (const float*)d_in[1];
    const float* Whh0 = (const float*)d_in[2];
    const float* b0   = (const float*)d_in[3];
    const float* Wih1 = (const float*)d_in[4];
    const float* Whh1 = (const float*)d_in[5];
    const float* b1   = (const float*)d_in[6];
    const float* Wc   = (const float*)d_in[7];
    const float* bc   = (const float*)d_in[8];
    float* out = (float*)d_out;

    dim3 grid(BATCH / NB);
    dim3 block(BLK);
    hipLaunchKernelGGL(lstm2_kernel, grid, block, 0, stream,
                       x, Wih0, Whh0, b0, Wih1, Whh1, b1, Wc, bc, out);
}